// Round 11
// baseline (233.638 us; speedup 1.0000x reference)
//
#include <hip/hip_runtime.h>
#include <hip/hip_bf16.h>

// SimCLR NT-Xent loss. B=4096, D=256, N=2B=8192 rows.
// loss = (1/N) sum_i [ log(denom_i) - log(pos_i) ]
//
// R23 = R22's fused kernel with the cooperative API replaced by a
// hand-rolled grid barrier. R22 failed with absmax=9.0 == |ref loss| ==
// "out never written" => hipLaunchCooperativeKernel never executed
// (graph-capture rejection suspected), NOT a logic/ordering bug.
// This version: plain <<<768,256>>> launch; arrive-count barriers in ws
// (zeroed per replay by a captured hipMemsetAsync); leader thread does
// __threadfence release -> atomicAdd -> acquire spin -> __threadfence
// (wbl2/inv = the documented cross-XCD mitigation; same semantics cg
// emits). Deadlock-safe by construction: grid = 768 = 256CU x 3 and
// launch_bounds(256,3) + 32KB LDS guarantee >=3 blocks/CU => ALL blocks
// resident; no block waits on an unscheduled block.
// Phase bodies byte-identical to verified R20: prep grid-strides 1024
// vbs, denom grid-strides 2080 tiles (65x32 triangular decode), loss on
// blocks 0-31. Goal: delete ~9us of inter-dispatch gaps (ledger: 86.3 =
// fill 42.5 + denom ~28 + prep ~4 + loss ~3 + gaps ~9).

#define NROWS 8192
#define BHALF 4096
#define DDIM  256
#define NBLK  768

typedef __attribute__((ext_vector_type(4))) int   i32x4;
typedef __attribute__((ext_vector_type(8))) int   i32x8;
typedef __attribute__((ext_vector_type(4))) float f32x4;

#define SCALE1 0x7F7F7F7F               // e8m0 biased-127 = 2^0 in every byte
#define TWO_LOG2E 2.8853900817779268f   // 2/ln(2): exp(2x) = exp2(x*TWO_LOG2E)

__device__ __forceinline__ void load_lds16(const unsigned char* g, unsigned char* l) {
    __builtin_amdgcn_global_load_lds(
        (const __attribute__((address_space(1))) void*)g,
        (__attribute__((address_space(3))) void*)l, 16, 0, 0);
}

// Arrive-count grid barrier (counters zeroed before launch each replay).
// Leader: release fence -> arrive -> acquire spin -> fence; then block sync.
__device__ __forceinline__ void grid_barrier(int* cnt) {
    __syncthreads();
    if (threadIdx.x == 0) {
        __threadfence();                              // release: wb L2
        atomicAdd(cnt, 1);                            // device-scope (m20)
        while (__hip_atomic_load(cnt, __ATOMIC_RELAXED,
                                 __HIP_MEMORY_SCOPE_AGENT) < NBLK)
            __builtin_amdgcn_s_sleep(2);
        __threadfence();                              // acquire: inv L1/L2
    }
    __syncthreads();
}

__global__ __launch_bounds__(256, 3) void fused_kernel(
        const float* __restrict__ z1, const float* __restrict__ z2,
        unsigned char* __restrict__ zn8, float* __restrict__ posPart,
        float* __restrict__ P, float* __restrict__ out, int* __restrict__ bar)
{
    __shared__ __align__(16) unsigned char sMem[32 * 1024];
    int bid  = blockIdx.x;
    int t    = threadIdx.x;
    int wave = t >> 6;
    int lane = t & 63;

    // ================= phase 1: prep (R20 body, grid-stride) =================
    {
        float* sp = (float*)sMem;
        for (int vb = bid; vb < 1024; vb += NBLK) {
            int i = vb * 4 + wave;
            float4 a = reinterpret_cast<const float4*>(z1 + (size_t)i * DDIM)[lane];
            float4 b = reinterpret_cast<const float4*>(z2 + (size_t)i * DDIM)[lane];
            float ss1 = a.x * a.x + a.y * a.y + a.z * a.z + a.w * a.w;
            float ss2 = b.x * b.x + b.y * b.y + b.z * b.z + b.w * b.w;
            float dd  = a.x * b.x + a.y * b.y + a.z * b.z + a.w * b.w;
            #pragma unroll
            for (int off = 32; off; off >>= 1) {
                ss1 += __shfl_xor(ss1, off);
                ss2 += __shfl_xor(ss2, off);
                dd  += __shfl_xor(dd, off);
            }
            float n1 = fmaxf(sqrtf(ss1), 1e-8f);
            float n2 = fmaxf(sqrtf(ss2), 1e-8f);
            float i1 = 1.0f / n1, i2 = 1.0f / n2;
            int pa = __builtin_amdgcn_cvt_pk_fp8_f32(a.x * i1, a.y * i1, 0, 0);
            pa     = __builtin_amdgcn_cvt_pk_fp8_f32(a.z * i1, a.w * i1, pa, 1);
            int pb = __builtin_amdgcn_cvt_pk_fp8_f32(b.x * i2, b.y * i2, 0, 0);
            pb     = __builtin_amdgcn_cvt_pk_fp8_f32(b.z * i2, b.w * i2, pb, 1);
            reinterpret_cast<int*>(zn8 + (size_t)i * DDIM)[lane] = pa;
            reinterpret_cast<int*>(zn8 + (size_t)(i + BHALF) * DDIM)[lane] = pb;
            if (lane == 0) sp[wave] = __logf(dd * i1 * i2);
            __syncthreads();
            if (t == 0) posPart[vb] = sp[0] + sp[1] + sp[2] + sp[3];
            __syncthreads();               // sp safe to overwrite next iter
        }
        if (bid == 0 && t == 0) out[0] = 0.0f;
    }
    grid_barrier(bar + 0);

    // ============ phase 2: denom (R20 body, grid-stride over tiles) ==========
    {
        unsigned char* buf0 = sMem;
        unsigned char* buf1 = sMem + 16384;
        int col  = lane & 15;
        int quad = lane >> 4;
        int wm = wave >> 1, wn = wave & 1;
        int rowL  = t >> 4;
        int chunk = (t & 15) ^ rowL;       // R13-verified XOR swizzle

        for (int tile = bid; tile < 2080; tile += NBLK) {
            __syncthreads();               // buffers free from previous tile

            int x = tile % 65, y = tile / 65;
            int bi, bj;
            if (x > y) { bi = y;      bj = x - 1;  }
            else       { bi = 63 - y; bj = 63 - x; }
            int iBase = bi * 128;
            int jBase = bj * 128;
            bool isDiag = (bi == bj);

            // ---- 2a: DMA A-half0 -> buf0, A-half1 -> buf1 ----
            {
                const unsigned char* gA = zn8 + (size_t)(iBase + rowL) * DDIM + chunk * 16;
                #pragma unroll
                for (int q = 0; q < 4; q++)
                    load_lds16(gA + q * 4096, buf0 + t * 16 + q * 4096);
                #pragma unroll
                for (int q = 0; q < 4; q++)
                    load_lds16(gA + 16384 + q * 4096, buf1 + t * 16 + q * 4096);
            }
            __syncthreads();               // A DMA landed

            // ---- 2b: A-fragments -> registers ----
            i32x8 af[4][2];
            {
                const unsigned char* aRow = (wm ? buf1 : buf0) + (size_t)col * DDIM;
                #pragma unroll
                for (int mt = 0; mt < 4; mt++)
                    #pragma unroll
                    for (int ks = 0; ks < 2; ks++) {
                        int g0 = ks * 8 + quad * 2;
                        i32x4 lo = *(const i32x4*)(aRow + mt * 16 * DDIM + ((g0    ) ^ col) * 16);
                        i32x4 hi = *(const i32x4*)(aRow + mt * 16 * DDIM + ((g0 + 1) ^ col) * 16);
                        af[mt][ks] = __builtin_shufflevector(lo, hi, 0, 1, 2, 3, 4, 5, 6, 7);
                    }
            }
            __syncthreads();               // A reads done -> buffers reusable

            // ---- 2c: DMA B0 -> buf0, B1 -> buf1; one drain ----
            {
                const unsigned char* gB = zn8 + (size_t)(jBase + rowL) * DDIM + chunk * 16;
                #pragma unroll
                for (int q = 0; q < 4; q++)
                    load_lds16(gB + q * 4096, buf0 + t * 16 + q * 4096);
                #pragma unroll
                for (int q = 0; q < 4; q++)
                    load_lds16(gB + 16384 + q * 4096, buf1 + t * 16 + q * 4096);
            }
            __syncthreads();               // B DMA landed

            float rs[4][4];
            #pragma unroll
            for (int mt = 0; mt < 4; mt++)
                #pragma unroll
                for (int r = 0; r < 4; r++) rs[mt][r] = 0.f;

            #pragma unroll
            for (int h = 0; h < 2; h++) {
                const unsigned char* bRow =
                    (h ? buf1 : buf0) + (size_t)(wn * 32 + col) * DDIM;

                #pragma unroll
                for (int nt = 0; nt < 2; nt++) {
                    i32x8 bfr[2];
                    #pragma unroll
                    for (int ks = 0; ks < 2; ks++) {
                        int g0 = ks * 8 + quad * 2;
                        i32x4 lo = *(const i32x4*)(bRow + nt * 16 * DDIM + ((g0    ) ^ col) * 16);
                        i32x4 hi = *(const i32x4*)(bRow + nt * 16 * DDIM + ((g0 + 1) ^ col) * 16);
                        bfr[ks] = __builtin_shufflevector(lo, hi, 0, 1, 2, 3, 4, 5, 6, 7);
                    }

                    float csn = 0.f;
                    #pragma unroll
                    for (int mt = 0; mt < 4; mt++) {
                        int gi = iBase + wm * 64 + mt * 16;
                        f32x4 acc = {0.f, 0.f, 0.f, 0.f};
                        acc = __builtin_amdgcn_mfma_scale_f32_16x16x128_f8f6f4(
                                  af[mt][0], bfr[0], acc, 0, 0, 0, SCALE1, 0, SCALE1);
                        acc = __builtin_amdgcn_mfma_scale_f32_16x16x128_f8f6f4(
                                  af[mt][1], bfr[1], acc, 0, 0, 0, SCALE1, 0, SCALE1);
                        bool dtile = (gi == jBase + h * 64 + wn * 32 + nt * 16);
                        #pragma unroll
                        for (int r = 0; r < 4; r++) {
                            float e = exp2f(acc[r] * TWO_LOG2E);
                            if (dtile && (quad * 4 + r) == col) e = 0.f;
                            rs[mt][r] += e;
                            csn       += e;
                        }
                    }

                    if (!isDiag) {
                        csn += __shfl_xor(csn, 16);
                        csn += __shfl_xor(csn, 32);
                        if (quad == 0)
                            P[(((size_t)bj * 64 + bi) * 2 + wm) * 128
                              + h * 64 + wn * 32 + nt * 16 + col] = csn;
                    }
                }
            }

            // row partials: single-writer per-wn stores, no barriers
            #pragma unroll
            for (int mt = 0; mt < 4; mt++)
                #pragma unroll
                for (int r = 0; r < 4; r++) {
                    float v = rs[mt][r];
                    v += __shfl_xor(v, 1);
                    v += __shfl_xor(v, 2);
                    v += __shfl_xor(v, 4);
                    v += __shfl_xor(v, 8);
                    rs[mt][r] = v;
                }
            if (col == 0) {
                float* Pr = P + (((size_t)bi * 64 + bj) * 2 + wn) * 128;
                #pragma unroll
                for (int mt = 0; mt < 4; mt++) {
                    f32x4 v4 = { rs[mt][0], rs[mt][1], rs[mt][2], rs[mt][3] };
                    *reinterpret_cast<f32x4*>(Pr + wm * 64 + mt * 16 + quad * 4) = v4;
                }
            }
        }
    }
    grid_barrier(bar + 16);               // separate cacheline

    // ================= phase 3: loss (R20 body, blocks 0-31) =================
    if (bid < 32) {
        float* sdata = (float*)sMem;
        int i = bid * 256 + t;
        int bi = i >> 7, r = i & 127;
        const float* p = P + ((size_t)bi << 14) + r;   // bi*64*2*128 + r
        float d0 = 0.f, d1 = 0.f, d2 = 0.f, d3 = 0.f;
        #pragma unroll
        for (int k = 0; k < 128; k += 4) {
            d0 += p[(k + 0) << 7];
            d1 += p[(k + 1) << 7];
            d2 += p[(k + 2) << 7];
            d3 += p[(k + 3) << 7];
        }
        float s = __logf((d0 + d1) + (d2 + d3));
        if (t < 32) s -= 2.0f * posPart[bid * 32 + t];
        #pragma unroll
        for (int off = 32; off; off >>= 1) s += __shfl_xor(s, off);
        if ((t & 63) == 0) sdata[t >> 6] = s;
        __syncthreads();
        if (t == 0)
            atomicAdd(out, (sdata[0] + sdata[1] + sdata[2] + sdata[3]) * (1.0f / NROWS));
    }
}

extern "C" void kernel_launch(void* const* d_in, const int* in_sizes, int n_in,
                              void* d_out, int out_size, void* d_ws, size_t ws_size,
                              hipStream_t stream) {
    const float* z1 = (const float*)d_in[0];
    const float* z2 = (const float*)d_in[1];
    float* outp = (float*)d_out;

    // ws: zn8 fp8 [8192*256] (2MB) | P f32[64][64][2][128] (4MB) |
    //     posPart f32[1024] (4KB) | barrier int[32] (2 cachelines)
    unsigned char* zn8 = (unsigned char*)d_ws;
    float* P       = (float*)((char*)d_ws + (size_t)NROWS * DDIM);
    float* posPart = P + (size_t)64 * 64 * 2 * 128;
    int*   bar     = (int*)(posPart + 1024);

    hipMemsetAsync(bar, 0, 32 * sizeof(int), stream);   // captured per replay
    fused_kernel<<<NBLK, 256, 0, stream>>>(z1, z2, zn8, posPart, P, outp, bar);
}

// Round 12
// 87.602 us; speedup vs baseline: 2.6670x; 2.6670x over previous
//
#include <hip/hip_runtime.h>
#include <hip/hip_bf16.h>

// SimCLR NT-Xent loss. B=4096, D=256, N=2B=8192 rows.
// loss = (1/N) sum_i [ log(denom_i) - log(pos_i) ]
//
// R24 = R20 (best verified 86.31us) + ONE lever: A-reuse across same-row
// tiles. R23 post-mortem: grid-wide sync costs ~75us/barrier on this chip
// (single-line atomics ping-pong across 8 XCD L2s) and gaps are only
// ~1-2us/boundary (R21 probe) -> fusion dead. Remaining headroom is
// denom's clean-L2 20.8us vs ~11 pipe (R21-measured): per-tile serial
// path ~2.56us dominated by {A-DMA wait, A-read} repeated per tile.
// This round: tiles grouped by row bi into <=3-tile groups -> 715 blocks
// (<=768 => single residency round @3/CU; fixes R16's 544@2/CU flaw),
// A staged + register-hoisted ONCE per block, then per tile the exact
// R20 {B0+B1 DMA -> barrier -> compute h0,h1} body. A staging traffic
// 66MB -> 23MB; per-block serial path 7.7 -> ~5.9us. Plain barriers,
// no counted-vmcnt, no tail clamps (variable trip count is fine).
// prep / loss / P scheme / workspace unchanged (verified).

#define NROWS 8192
#define BHALF 4096
#define DDIM  256

typedef __attribute__((ext_vector_type(4))) int   i32x4;
typedef __attribute__((ext_vector_type(8))) int   i32x8;
typedef __attribute__((ext_vector_type(4))) float f32x4;

#define SCALE1 0x7F7F7F7F               // e8m0 biased-127 = 2^0 in every byte
#define TWO_LOG2E 2.8853900817779268f   // 2/ln(2): exp(2x) = exp2(x*TWO_LOG2E)

__device__ __forceinline__ void load_lds16(const unsigned char* g, unsigned char* l) {
    __builtin_amdgcn_global_load_lds(
        (const __attribute__((address_space(1))) void*)g,
        (__attribute__((address_space(3))) void*)l, 16, 0, 0);
}

// Kernel 1: norms + fp8-normalized matrix + positive-pair log partials +
// out zero-init. (unchanged, verified)
__global__ __launch_bounds__(256) void prep_kernel(const float* __restrict__ z1,
                                                   const float* __restrict__ z2,
                                                   unsigned char* __restrict__ zn8,
                                                   float* __restrict__ posPart,
                                                   float* __restrict__ out) {
    __shared__ float sp[4];
    int wave = threadIdx.x >> 6;
    int lane = threadIdx.x & 63;
    int i    = blockIdx.x * 4 + wave;
    float4 a = reinterpret_cast<const float4*>(z1 + (size_t)i * DDIM)[lane];
    float4 b = reinterpret_cast<const float4*>(z2 + (size_t)i * DDIM)[lane];
    float ss1 = a.x * a.x + a.y * a.y + a.z * a.z + a.w * a.w;
    float ss2 = b.x * b.x + b.y * b.y + b.z * b.z + b.w * b.w;
    float dd  = a.x * b.x + a.y * b.y + a.z * b.z + a.w * b.w;
    #pragma unroll
    for (int off = 32; off; off >>= 1) {
        ss1 += __shfl_xor(ss1, off);
        ss2 += __shfl_xor(ss2, off);
        dd  += __shfl_xor(dd, off);
    }
    float n1 = fmaxf(sqrtf(ss1), 1e-8f);
    float n2 = fmaxf(sqrtf(ss2), 1e-8f);
    float i1 = 1.0f / n1, i2 = 1.0f / n2;
    int pa = __builtin_amdgcn_cvt_pk_fp8_f32(a.x * i1, a.y * i1, 0, 0);
    pa     = __builtin_amdgcn_cvt_pk_fp8_f32(a.z * i1, a.w * i1, pa, 1);
    int pb = __builtin_amdgcn_cvt_pk_fp8_f32(b.x * i2, b.y * i2, 0, 0);
    pb     = __builtin_amdgcn_cvt_pk_fp8_f32(b.z * i2, b.w * i2, pb, 1);
    reinterpret_cast<int*>(zn8 + (size_t)i * DDIM)[lane] = pa;
    reinterpret_cast<int*>(zn8 + (size_t)(i + BHALF) * DDIM)[lane] = pb;
    if (lane == 0) sp[wave] = __logf(dd * i1 * i2);
    if (blockIdx.x == 0 && threadIdx.x == 64) out[0] = 0.0f;
    __syncthreads();
    if (threadIdx.x == 0)
        posPart[blockIdx.x] = sp[0] + sp[1] + sp[2] + sp[3];
}

// Kernel 2: row-grouped triangular tiles; A staged+hoisted once per block,
// then per tile the R20 {B DMA -> barrier -> compute} body. 715 blocks.
__global__ __launch_bounds__(256, 3) void denom_kernel(const unsigned char* __restrict__ zn8,
                                                       float* __restrict__ P) {
    __shared__ __align__(16) unsigned char sMem[32 * 1024];
    unsigned char* buf0 = sMem;
    unsigned char* buf1 = sMem + 16384;

    // block -> (bi, bjStart): row bi has ceil((64-bi)/3) groups of <=3 tiles
    int b = blockIdx.x;
    int bi = 0;
    while (true) { int c = (66 - bi) / 3; if (b < c) break; b -= c; bi++; }
    int bjStart = bi + b * 3;
    int ntiles  = 64 - bjStart; if (ntiles > 3) ntiles = 3;
    int iBase   = bi * 128;

    int t    = threadIdx.x;
    int lane = t & 63;
    int wave = t >> 6;
    int col  = lane & 15;
    int quad = lane >> 4;
    int wm = wave >> 1, wn = wave & 1;

    // staging: 64-row half -> 16KB buffer; row (q*16 + rowL) at slab
    // q*4096 + rowL*256; 16B slot (t&15) holds k-chunk (t&15)^rowL
    // (R13-verified XOR swizzle, matched on read by ^col since col==row%16)
    int rowL  = t >> 4;
    int chunk = (t & 15) ^ rowL;

    // ---- stage A once: half0 -> buf0, half1 -> buf1 ----
    {
        const unsigned char* gA = zn8 + (size_t)(iBase + rowL) * DDIM + chunk * 16;
        #pragma unroll
        for (int q = 0; q < 4; q++)
            load_lds16(gA + q * 4096, buf0 + t * 16 + q * 4096);
        #pragma unroll
        for (int q = 0; q < 4; q++)
            load_lds16(gA + 16384 + q * 4096, buf1 + t * 16 + q * 4096);
    }
    __syncthreads();                    // A DMA landed

    // ---- A-fragments -> registers once (wave-pair reads own half) ----
    i32x8 af[4][2];
    {
        const unsigned char* aRow = (wm ? buf1 : buf0) + (size_t)col * DDIM;
        #pragma unroll
        for (int mt = 0; mt < 4; mt++)
            #pragma unroll
            for (int ks = 0; ks < 2; ks++) {
                int g0 = ks * 8 + quad * 2;
                i32x4 lo = *(const i32x4*)(aRow + mt * 16 * DDIM + ((g0    ) ^ col) * 16);
                i32x4 hi = *(const i32x4*)(aRow + mt * 16 * DDIM + ((g0 + 1) ^ col) * 16);
                af[mt][ks] = __builtin_shufflevector(lo, hi, 0, 1, 2, 3, 4, 5, 6, 7);
            }
    }
    __syncthreads();                    // all A reads done -> buffers reusable

    // ---- per tile: B0 -> buf0, B1 -> buf1; one drain; compute both ----
    #pragma unroll 1
    for (int k = 0; k < ntiles; k++) {
        int bj     = bjStart + k;
        int jBase  = bj * 128;
        bool isDiag = (bi == bj);

        if (k) __syncthreads();         // prev tile's LDS reads done

        {
            const unsigned char* gB = zn8 + (size_t)(jBase + rowL) * DDIM + chunk * 16;
            #pragma unroll
            for (int q = 0; q < 4; q++)
                load_lds16(gB + q * 4096, buf0 + t * 16 + q * 4096);
            #pragma unroll
            for (int q = 0; q < 4; q++)
                load_lds16(gB + 16384 + q * 4096, buf1 + t * 16 + q * 4096);
        }
        __syncthreads();                // B DMA landed

        float rs[4][4];                 // row-sums over both halves
        #pragma unroll
        for (int mt = 0; mt < 4; mt++)
            #pragma unroll
            for (int r = 0; r < 4; r++) rs[mt][r] = 0.f;

        #pragma unroll
        for (int h = 0; h < 2; h++) {
            const unsigned char* bRow =
                (h ? buf1 : buf0) + (size_t)(wn * 32 + col) * DDIM;

            #pragma unroll
            for (int nt = 0; nt < 2; nt++) {
                i32x8 bfr[2];
                #pragma unroll
                for (int ks = 0; ks < 2; ks++) {
                    int g0 = ks * 8 + quad * 2;
                    i32x4 lo = *(const i32x4*)(bRow + nt * 16 * DDIM + ((g0    ) ^ col) * 16);
                    i32x4 hi = *(const i32x4*)(bRow + nt * 16 * DDIM + ((g0 + 1) ^ col) * 16);
                    bfr[ks] = __builtin_shufflevector(lo, hi, 0, 1, 2, 3, 4, 5, 6, 7);
                }

                float csn = 0.f;
                #pragma unroll
                for (int mt = 0; mt < 4; mt++) {
                    int gi = iBase + wm * 64 + mt * 16;
                    f32x4 acc = {0.f, 0.f, 0.f, 0.f};
                    acc = __builtin_amdgcn_mfma_scale_f32_16x16x128_f8f6f4(
                              af[mt][0], bfr[0], acc, 0, 0, 0, SCALE1, 0, SCALE1);
                    acc = __builtin_amdgcn_mfma_scale_f32_16x16x128_f8f6f4(
                              af[mt][1], bfr[1], acc, 0, 0, 0, SCALE1, 0, SCALE1);
                    bool dtile = (gi == jBase + h * 64 + wn * 32 + nt * 16);
                    #pragma unroll
                    for (int r = 0; r < 4; r++) {
                        float e = exp2f(acc[r] * TWO_LOG2E);
                        if (dtile && (quad * 4 + r) == col) e = 0.f;
                        rs[mt][r] += e;
                        csn       += e;
                    }
                }

                // col partial: reduce over quads, store per-wm partial at
                // slot (bj, bi, s=wm). Single-writer, no atomics.
                if (!isDiag) {
                    csn += __shfl_xor(csn, 16);
                    csn += __shfl_xor(csn, 32);
                    if (quad == 0)
                        P[(((size_t)bj * 64 + bi) * 2 + wm) * 128
                          + h * 64 + wn * 32 + nt * 16 + col] = csn;
                }
            }
        }

        // row partials: reduce 16 col-lanes, store per-wn partial at slot
        // (bi, bj, s=wn). Pure register path — no barriers.
        #pragma unroll
        for (int mt = 0; mt < 4; mt++)
            #pragma unroll
            for (int r = 0; r < 4; r++) {
                float v = rs[mt][r];
                v += __shfl_xor(v, 1);
                v += __shfl_xor(v, 2);
                v += __shfl_xor(v, 4);
                v += __shfl_xor(v, 8);
                rs[mt][r] = v;
            }
        if (col == 0) {
            float* Pr = P + (((size_t)bi * 64 + bj) * 2 + wn) * 128;
            #pragma unroll
            for (int mt = 0; mt < 4; mt++) {
                f32x4 v4 = { rs[mt][0], rs[mt][1], rs[mt][2], rs[mt][3] };
                *reinterpret_cast<f32x4*>(Pr + wm * 64 + mt * 16 + quad * 4) = v4;
            }
        }
    }
}

// Kernel 3: per-row 128-slot reduction of P (coalesced, L2-resident) + final
// loss reduction, 32 blocks, atomic into prep-zeroed out[0]. (verified)
__global__ __launch_bounds__(256) void loss_kernel(const float* __restrict__ posPart,
                                                   const float* __restrict__ P,
                                                   float* __restrict__ out) {
    __shared__ float sdata[4];
    int t = threadIdx.x;
    int i = blockIdx.x * 256 + t;
    int bi = i >> 7, r = i & 127;
    const float* p = P + ((size_t)bi << 14) + r;   // bi*64*2*128 + r
    float d0 = 0.f, d1 = 0.f, d2 = 0.f, d3 = 0.f;
    #pragma unroll
    for (int k = 0; k < 128; k += 4) {
        d0 += p[(k + 0) << 7];
        d1 += p[(k + 1) << 7];
        d2 += p[(k + 2) << 7];
        d3 += p[(k + 3) << 7];
    }
    float s = __logf((d0 + d1) + (d2 + d3));
    if (t < 32) s -= 2.0f * posPart[blockIdx.x * 32 + t];
    #pragma unroll
    for (int off = 32; off; off >>= 1) s += __shfl_xor(s, off);
    if ((t & 63) == 0) sdata[t >> 6] = s;
    __syncthreads();
    if (t == 0)
        atomicAdd(out, (sdata[0] + sdata[1] + sdata[2] + sdata[3]) * (1.0f / NROWS));
}

extern "C" void kernel_launch(void* const* d_in, const int* in_sizes, int n_in,
                              void* d_out, int out_size, void* d_ws, size_t ws_size,
                              hipStream_t stream) {
    const float* z1 = (const float*)d_in[0];
    const float* z2 = (const float*)d_in[1];

    // ws: zn8 fp8 [8192*256] (2 MB) | P f32[64][64][2][128] (4 MB) | posPart f32[1024]
    unsigned char* zn8 = (unsigned char*)d_ws;
    float* P       = (float*)((char*)d_ws + (size_t)NROWS * DDIM);
    float* posPart = P + (size_t)64 * 64 * 2 * 128;

    prep_kernel<<<BHALF / 4, 256, 0, stream>>>(z1, z2, zn8, posPart, (float*)d_out);
    denom_kernel<<<715, 256, 0, stream>>>(zn8, P);   // sum_{bi} ceil((64-bi)/3)
    loss_kernel<<<NROWS / 256, 256, 0, stream>>>(posPart, P, (float*)d_out);
}

// Round 13
// 87.001 us; speedup vs baseline: 2.6855x; 1.0069x over previous
//
#include <hip/hip_runtime.h>
#include <hip/hip_bf16.h>

// SimCLR NT-Xent loss. B=4096, D=256, N=2B=8192 rows.
// loss = (1/N) sum_i [ log(denom_i) - log(pos_i) ]
//
// R25 = R20 verbatim (best verified: 86.31us) — final revert, banking the
// best kernel. Session ceiling arithmetic (9 denom structures tested):
//   total = fill prefix ~42.4us (256MiB @ 6.35TB/s, 80% HBM peak — harness
//           poison fill, AT its roofline, not ours)
//         + prep ~5 + denom ~28 (clean-L2 20.8 [R21 probe]; +7 storm;
//           pipe floor ~11 — unreachable: 6 restructures attacked the
//           latency gap from both directions, all neutral or worse)
//         + loss ~3.5 + gaps ~3  ==> ~86.4us. Measured: 86.31.
// Exonerated/refuted with evidence: atomics (R13), LDS-staging overhead
// (R17/R19), register pinning+caps (R18), occupancy 3->4/CU (R20 vs R13),
// multi-tile counted-vmcnt pipeline (R16), A-reuse (R24), kernel fusion
// (R22 coop rejected by graph capture; R23 hand barrier ~75us/sync from
// cross-XCD cacheline ping-pong).
//
// Structure: prep (fp8-normalize + pos-pair partials) -> denom (triangular
// 128x128 fp8 scaled-MFMA tiles, 32KB LDS, A DMA-staged then held in regs,
// B double-buffered, exp + row/col partial sums, single-writer P stores,
// no atomics/no init) -> loss (P reduction + final logs).

#define NROWS 8192
#define BHALF 4096
#define DDIM  256

typedef __attribute__((ext_vector_type(4))) int   i32x4;
typedef __attribute__((ext_vector_type(8))) int   i32x8;
typedef __attribute__((ext_vector_type(4))) float f32x4;

#define SCALE1 0x7F7F7F7F               // e8m0 biased-127 = 2^0 in every byte
#define TWO_LOG2E 2.8853900817779268f   // 2/ln(2): exp(2x) = exp2(x*TWO_LOG2E)

__device__ __forceinline__ void load_lds16(const unsigned char* g, unsigned char* l) {
    __builtin_amdgcn_global_load_lds(
        (const __attribute__((address_space(1))) void*)g,
        (__attribute__((address_space(3))) void*)l, 16, 0, 0);
}

// Kernel 1: norms + fp8-normalized matrix + positive-pair log partials +
// out zero-init. (verified)
__global__ __launch_bounds__(256) void prep_kernel(const float* __restrict__ z1,
                                                   const float* __restrict__ z2,
                                                   unsigned char* __restrict__ zn8,
                                                   float* __restrict__ posPart,
                                                   float* __restrict__ out) {
    __shared__ float sp[4];
    int wave = threadIdx.x >> 6;
    int lane = threadIdx.x & 63;
    int i    = blockIdx.x * 4 + wave;
    float4 a = reinterpret_cast<const float4*>(z1 + (size_t)i * DDIM)[lane];
    float4 b = reinterpret_cast<const float4*>(z2 + (size_t)i * DDIM)[lane];
    float ss1 = a.x * a.x + a.y * a.y + a.z * a.z + a.w * a.w;
    float ss2 = b.x * b.x + b.y * b.y + b.z * b.z + b.w * b.w;
    float dd  = a.x * b.x + a.y * b.y + a.z * b.z + a.w * b.w;
    #pragma unroll
    for (int off = 32; off; off >>= 1) {
        ss1 += __shfl_xor(ss1, off);
        ss2 += __shfl_xor(ss2, off);
        dd  += __shfl_xor(dd, off);
    }
    float n1 = fmaxf(sqrtf(ss1), 1e-8f);
    float n2 = fmaxf(sqrtf(ss2), 1e-8f);
    float i1 = 1.0f / n1, i2 = 1.0f / n2;
    int pa = __builtin_amdgcn_cvt_pk_fp8_f32(a.x * i1, a.y * i1, 0, 0);
    pa     = __builtin_amdgcn_cvt_pk_fp8_f32(a.z * i1, a.w * i1, pa, 1);
    int pb = __builtin_amdgcn_cvt_pk_fp8_f32(b.x * i2, b.y * i2, 0, 0);
    pb     = __builtin_amdgcn_cvt_pk_fp8_f32(b.z * i2, b.w * i2, pb, 1);
    reinterpret_cast<int*>(zn8 + (size_t)i * DDIM)[lane] = pa;
    reinterpret_cast<int*>(zn8 + (size_t)(i + BHALF) * DDIM)[lane] = pb;
    if (lane == 0) sp[wave] = __logf(dd * i1 * i2);
    if (blockIdx.x == 0 && threadIdx.x == 64) out[0] = 0.0f;
    __syncthreads();
    if (threadIdx.x == 0)
        posPart[blockIdx.x] = sp[0] + sp[1] + sp[2] + sp[3];
}

// Kernel 2: triangular 128x128 tiles, 32KB LDS, A DMA-staged per wave-pair.
// (verified, best)
__global__ __launch_bounds__(256, 3) void denom_kernel(const unsigned char* __restrict__ zn8,
                                                       float* __restrict__ P) {
    __shared__ __align__(16) unsigned char sMem[32 * 1024];
    unsigned char* buf0 = sMem;
    unsigned char* buf1 = sMem + 16384;

    // triangular decode: 65x32 grid -> {(bi,bj) : 0 <= bi <= bj < 64}
    int x = blockIdx.x, y = blockIdx.y;
    int bi, bj;
    if (x > y) { bi = y;      bj = x - 1;  }
    else       { bi = 63 - y; bj = 63 - x; }
    int iBase = bi * 128;
    int jBase = bj * 128;
    bool isDiag = (bi == bj);

    int t    = threadIdx.x;
    int lane = t & 63;
    int wave = t >> 6;
    int col  = lane & 15;
    int quad = lane >> 4;
    int wm = wave >> 1, wn = wave & 1;

    // staging: 64-row half -> 16KB buffer; row (q*16 + rowL) at slab
    // q*4096 + rowL*256; 16B slot (t&15) holds k-chunk (t&15)^rowL
    // (verified XOR swizzle, matched on read by ^col since col==row%16)
    int rowL  = t >> 4;
    int chunk = (t & 15) ^ rowL;

    // ---- phase 1: DMA A-half0 -> buf0, A-half1 -> buf1 ----
    {
        const unsigned char* gA = zn8 + (size_t)(iBase + rowL) * DDIM + chunk * 16;
        #pragma unroll
        for (int q = 0; q < 4; q++)
            load_lds16(gA + q * 4096, buf0 + t * 16 + q * 4096);
        #pragma unroll
        for (int q = 0; q < 4; q++)
            load_lds16(gA + 16384 + q * 4096, buf1 + t * 16 + q * 4096);
    }
    __syncthreads();                    // A DMA landed

    // ---- phase 2: A-fragments -> registers (wave-pair reads own half) ----
    i32x8 af[4][2];
    {
        const unsigned char* aRow = (wm ? buf1 : buf0) + (size_t)col * DDIM;
        #pragma unroll
        for (int mt = 0; mt < 4; mt++)
            #pragma unroll
            for (int ks = 0; ks < 2; ks++) {
                int g0 = ks * 8 + quad * 2;
                i32x4 lo = *(const i32x4*)(aRow + mt * 16 * DDIM + ((g0    ) ^ col) * 16);
                i32x4 hi = *(const i32x4*)(aRow + mt * 16 * DDIM + ((g0 + 1) ^ col) * 16);
                af[mt][ks] = __builtin_shufflevector(lo, hi, 0, 1, 2, 3, 4, 5, 6, 7);
            }
    }
    __syncthreads();                    // all A reads done -> buffers reusable

    // ---- phase 3: DMA B0 -> buf0, B1 -> buf1; one drain; compute both ----
    {
        const unsigned char* gB = zn8 + (size_t)(jBase + rowL) * DDIM + chunk * 16;
        #pragma unroll
        for (int q = 0; q < 4; q++)
            load_lds16(gB + q * 4096, buf0 + t * 16 + q * 4096);
        #pragma unroll
        for (int q = 0; q < 4; q++)
            load_lds16(gB + 16384 + q * 4096, buf1 + t * 16 + q * 4096);
    }
    __syncthreads();                    // B DMA landed; no more barriers

    float rs[4][4];                     // row-sums over both halves
    #pragma unroll
    for (int mt = 0; mt < 4; mt++)
        #pragma unroll
        for (int r = 0; r < 4; r++) rs[mt][r] = 0.f;

    #pragma unroll
    for (int h = 0; h < 2; h++) {
        const unsigned char* bRow =
            (h ? buf1 : buf0) + (size_t)(wn * 32 + col) * DDIM;

        // stream B fragments one 16-row block per nt (16 regs live)
        #pragma unroll
        for (int nt = 0; nt < 2; nt++) {
            i32x8 bfr[2];
            #pragma unroll
            for (int ks = 0; ks < 2; ks++) {
                int g0 = ks * 8 + quad * 2;
                i32x4 lo = *(const i32x4*)(bRow + nt * 16 * DDIM + ((g0    ) ^ col) * 16);
                i32x4 hi = *(const i32x4*)(bRow + nt * 16 * DDIM + ((g0 + 1) ^ col) * 16);
                bfr[ks] = __builtin_shufflevector(lo, hi, 0, 1, 2, 3, 4, 5, 6, 7);
            }

            float csn = 0.f;
            #pragma unroll
            for (int mt = 0; mt < 4; mt++) {
                int gi = iBase + wm * 64 + mt * 16;
                f32x4 acc = {0.f, 0.f, 0.f, 0.f};
                acc = __builtin_amdgcn_mfma_scale_f32_16x16x128_f8f6f4(
                          af[mt][0], bfr[0], acc, 0, 0, 0, SCALE1, 0, SCALE1);
                acc = __builtin_amdgcn_mfma_scale_f32_16x16x128_f8f6f4(
                          af[mt][1], bfr[1], acc, 0, 0, 0, SCALE1, 0, SCALE1);
                bool dtile = (gi == jBase + h * 64 + wn * 32 + nt * 16);
                #pragma unroll
                for (int r = 0; r < 4; r++) {
                    float e = exp2f(acc[r] * TWO_LOG2E);
                    if (dtile && (quad * 4 + r) == col) e = 0.f;
                    rs[mt][r] += e;
                    csn       += e;
                }
            }

            // col partial: reduce over quads, store per-wm partial at slot
            // (bj, bi, s=wm). Single-writer, no atomics.
            if (!isDiag) {
                csn += __shfl_xor(csn, 16);
                csn += __shfl_xor(csn, 32);
                if (quad == 0)
                    P[(((size_t)bj * 64 + bi) * 2 + wm) * 128
                      + h * 64 + wn * 32 + nt * 16 + col] = csn;
            }
        }
    }

    // ---- row partials: reduce 16 col-lanes, store per-wn partial at slot
    //      (bi, bj, s=wn). Pure register path — no barriers. ----
    #pragma unroll
    for (int mt = 0; mt < 4; mt++)
        #pragma unroll
        for (int r = 0; r < 4; r++) {
            float v = rs[mt][r];
            v += __shfl_xor(v, 1);
            v += __shfl_xor(v, 2);
            v += __shfl_xor(v, 4);
            v += __shfl_xor(v, 8);
            rs[mt][r] = v;
        }
    if (col == 0) {
        float* Pr = P + (((size_t)bi * 64 + bj) * 2 + wn) * 128;
        #pragma unroll
        for (int mt = 0; mt < 4; mt++) {
            f32x4 v4 = { rs[mt][0], rs[mt][1], rs[mt][2], rs[mt][3] };
            *reinterpret_cast<f32x4*>(Pr + wm * 64 + mt * 16 + quad * 4) = v4;
        }
    }
}

// Kernel 3: per-row 128-slot reduction of P (coalesced, L2-resident) + final
// loss reduction, 32 blocks, atomic into prep-zeroed out[0]. (verified)
__global__ __launch_bounds__(256) void loss_kernel(const float* __restrict__ posPart,
                                                   const float* __restrict__ P,
                                                   float* __restrict__ out) {
    __shared__ float sdata[4];
    int t = threadIdx.x;
    int i = blockIdx.x * 256 + t;
    int bi = i >> 7, r = i & 127;
    const float* p = P + ((size_t)bi << 14) + r;   // bi*64*2*128 + r
    float d0 = 0.f, d1 = 0.f, d2 = 0.f, d3 = 0.f;
    #pragma unroll
    for (int k = 0; k < 128; k += 4) {
        d0 += p[(k + 0) << 7];
        d1 += p[(k + 1) << 7];
        d2 += p[(k + 2) << 7];
        d3 += p[(k + 3) << 7];
    }
    float s = __logf((d0 + d1) + (d2 + d3));
    if (t < 32) s -= 2.0f * posPart[blockIdx.x * 32 + t];
    #pragma unroll
    for (int off = 32; off; off >>= 1) s += __shfl_xor(s, off);
    if ((t & 63) == 0) sdata[t >> 6] = s;
    __syncthreads();
    if (t == 0)
        atomicAdd(out, (sdata[0] + sdata[1] + sdata[2] + sdata[3]) * (1.0f / NROWS));
}

extern "C" void kernel_launch(void* const* d_in, const int* in_sizes, int n_in,
                              void* d_out, int out_size, void* d_ws, size_t ws_size,
                              hipStream_t stream) {
    const float* z1 = (const float*)d_in[0];
    const float* z2 = (const float*)d_in[1];

    // ws: zn8 fp8 [8192*256] (2 MB) | P f32[64][64][2][128] (4 MB) | posPart f32[1024]
    unsigned char* zn8 = (unsigned char*)d_ws;
    float* P       = (float*)((char*)d_ws + (size_t)NROWS * DDIM);
    float* posPart = P + (size_t)64 * 64 * 2 * 128;

    prep_kernel<<<BHALF / 4, 256, 0, stream>>>(z1, z2, zn8, posPart, (float*)d_out);
    denom_kernel<<<dim3(65, 32), 256, 0, stream>>>(zn8, P);
    loss_kernel<<<NROWS / 256, 256, 0, stream>>>(posPart, P, (float*)d_out);
}